// Round 6
// baseline (244.066 us; speedup 1.0000x reference)
//
#include <hip/hip_runtime.h>
#include <hip/hip_fp16.h>

#define BB   128
#define NN   4096
#define OUTD 64
#define P1   64
#define P2   128
#define P3   256
#define R1   256
#define R2   128
#define CHUNK 64
#define NCHK (NN / CHUNK)     // 64 chunk positions per batch
#define GPB  6                // blocks per batch
#define PGRID (BB * GPB)      // 768 = 3 blocks/CU exactly resident

typedef _Float16 half8 __attribute__((ext_vector_type(8)));
typedef _Float16 half4 __attribute__((ext_vector_type(4)));
typedef float    f32x4 __attribute__((ext_vector_type(4)));

// workspace layout
#define AGG_OFF 0                        // 128*256 u32 (fp32 bits) = 131072 B
#define W2F_OFF (BB * P3 * 4)            // W2 A-frags fp16, 16 frags x 1KB = 16384 B
#define W3F_OFF (W2F_OFF + P2 * P1 * 2)  // W3 A-frags fp16, 64 frags x 1KB = 65536 B

// prep: zero agg + swizzle w2/w3 into MFMA A-fragment order.
// frag f element (l, j): W[ch = mt*16 + (l&15)][k = ks*32 + (l>>4)*8 + j]
__global__ void prep_kernel(const float* __restrict__ w2, const float* __restrict__ w3,
                            unsigned char* ws) {
  int idx = blockIdx.x * 256 + threadIdx.x;
  if (idx < BB * P3) ((unsigned*)(ws + AGG_OFF))[idx] = 0u;   // agg = +0.0f
  _Float16* W2F = (_Float16*)(ws + W2F_OFF);
  _Float16* W3F = (_Float16*)(ws + W3F_OFF);
  if (idx < P1 * P2) {                       // 16 frags (mt:8, ks:2)
    int f = idx >> 9, rem = idx & 511, l = rem >> 3, j = rem & 7;
    int mt = f >> 1, ks = f & 1;
    int ch = mt * 16 + (l & 15), k = ks * 32 + (l >> 4) * 8 + j;
    W2F[idx] = (_Float16)w2[k * P2 + ch];
  }
  int i2 = idx - P1 * P2;
  if (i2 >= 0 && i2 < P2 * P3) {             // 64 frags (mt:16, ks:4)
    int f = i2 >> 9, rem = i2 & 511, l = rem >> 3, j = rem & 7;
    int mt = f >> 2, ks = f & 3;
    int ch = mt * 16 + (l & 15), k = ks * 32 + (l >> 4) * 8 + j;
    W3F[i2] = (_Float16)w3[k * P3 + ch];
  }
}

// phi: persistent blocks, grid = 768 (3/CU @ (256,3), the ONLY proven
// no-spill point for this body -- budgets <=128 spilled in R1/R4/R5).
// Block bid: batch b = bid&127, group g = bid>>7; handles chunks g, g+6, ...
// while c*64 < len. b constant per block enables the key win:
//  * masked-max accumulated in REGISTERS (rm[4][4], statically indexed via
//    unrolled s-loop -- dynamic indexing would go to scratch) across all the
//    block's items; shuffle-reduce + atomicMax ONCE per block. Removes the
//    per-item 64 shuffles + 16 atomics + vmcnt drain at next barrier
//    (~400-700 cy/item, the largest stall in the R3 chain analysis).
//  * a2/a3c weight frags + setup loaded once per block (amortized 5-11x).
//  * next-item points prefetched right after L1 consumes xy (lands under
//    L2+L3, ~1500 cy of cover).
// Barrier audit per item (uniform trip count; zero-item blocks exit before
// any barrier): [L1 w:sH1] bar1 [L2 r:sH1 w:sH2] bar2 [bf3 r:sH2; L3 regs].
// Item k+1's sH1 writes happen after bar2(k) (sH1 reads done); its sH2
// writes after bar1(k+1), by which point every wave consumed bf3(k). Safe.
// R4 lesson intact: bf3 never live across another phase; single a3 buffer,
// refilled in place after last use, wrapping (s+1)&3 so slab 0 is ready for
// the next item (next item's L1+L2 covers the latency).
__launch_bounds__(256, 3)
__global__ void phi_kernel(const float* __restrict__ pts, const int* __restrict__ lengths,
                           const float* __restrict__ w1, const float* __restrict__ b1,
                           const float* __restrict__ b2, const float* __restrict__ b3,
                           unsigned char* ws) {
  __shared__ __align__(16) _Float16 sH1[8][CHUNK][8];    //  8 KB
  __shared__ __align__(16) _Float16 sH2[16][CHUNK][8];   // 16 KB

  int bid = blockIdx.x;
  int b = bid & (BB - 1), g = bid >> 7;
  int len = lengths[b];
  if (g * CHUNK >= len) return;           // block-uniform, before any barrier

  int t = threadIdx.x;
  int w = t >> 6, l = t & 63;
  int ml = l & 15, q = l >> 4;

  const half8* W2F = (const half8*)(ws + W2F_OFF);  // 64 half8 per frag
  const half8* W3F = (const half8*)(ws + W3F_OFF);
  const float2* Pp = (const float2*)pts + (size_t)b * NN;
  unsigned* aggU = (unsigned*)(ws + AGG_OFF) + b * P3;

  // block-resident weight fragments
  half8 a2[2][2];
#pragma unroll
  for (int mt2 = 0; mt2 < 2; ++mt2)
#pragma unroll
    for (int ks = 0; ks < 2; ++ks)
      a2[mt2][ks] = W2F[((w * 2 + mt2) * 2 + ks) * 64 + l];
  half8 a3c[4];                 // invariant: slab-0 frags at item top
#pragma unroll
  for (int ks = 0; ks < 4; ++ks)
    a3c[ks] = W3F[((w * 4 + 0) * 4 + ks) * 64 + l];

  float2 xy = Pp[g * CHUNK + l];          // first item's points

  // cross-item max accumulator: thread holds (q,r) for slabs s=0..3.
  // rm >= 0 always (ReLU) and agg init is +0.0f, so starting at 0 is exact.
  float rm[4][4] = {};

  for (int c = g; c * CHUNK < len; c += GPB) {
    int v = min(CHUNK, len - c * CHUNK);

    // ---- L1 (K=2, VALU fp32): wave w computes ch [16w,16w+16) for 64 pts
    {
      half8 h8[2];
#pragma unroll
      for (int j = 0; j < 16; ++j) {
        int jj = w * 16 + j;                            // wave-uniform -> s_loads
        float h = fmaf(xy.y, w1[P1 + jj], fmaf(xy.x, w1[jj], b1[jj]));
        h8[j >> 3][j & 7] = (_Float16)fmaxf(h, 0.f);
      }
      *(half8*)&sH1[w * 2][l][0]     = h8[0];
      *(half8*)&sH1[w * 2 + 1][l][0] = h8[1];
    }
    // prefetch next item's points (clamped index stays in-bounds; value
    // unused on last item). Lands during L2+L3.
    xy = Pp[min(c + GPB, NCHK - 1) * CHUNK + l];
    __syncthreads();                      // bar1

    // ---- L2: h2^T[128][64] = W2^T x h1^T  (16 MFMAs/wave)
    {
      f32x4 acc2[2][4] = {};
#pragma unroll
      for (int ks = 0; ks < 2; ++ks) {
        half8 bf[4];
#pragma unroll
        for (int nt = 0; nt < 4; ++nt)
          bf[nt] = *(const half8*)&sH1[ks * 4 + q][nt * 16 + ml][0];
#pragma unroll
        for (int mt2 = 0; mt2 < 2; ++mt2)
#pragma unroll
          for (int nt = 0; nt < 4; ++nt)
            acc2[mt2][nt] = __builtin_amdgcn_mfma_f32_16x16x32_f16(
                a2[mt2][ks], bf[nt], acc2[mt2][nt], 0, 0, 0);
      }
      // epilogue: bias+ReLU; lane holds 4 consecutive ch -> packed 8B writes
#pragma unroll
      for (int mt2 = 0; mt2 < 2; ++mt2) {
        float4 b2v = *(const float4*)&b2[(w * 2 + mt2) * 16 + q * 4];
#pragma unroll
        for (int nt = 0; nt < 4; ++nt) {
          half4 hp;
          hp[0] = (_Float16)fmaxf(acc2[mt2][nt][0] + b2v.x, 0.f);
          hp[1] = (_Float16)fmaxf(acc2[mt2][nt][1] + b2v.y, 0.f);
          hp[2] = (_Float16)fmaxf(acc2[mt2][nt][2] + b2v.z, 0.f);
          hp[3] = (_Float16)fmaxf(acc2[mt2][nt][3] + b2v.w, 0.f);
          *(half4*)&sH2[(w * 2 + mt2) * 2 + (q >> 1)][nt * 16 + ml][(q & 1) * 4] = hp;
        }
      }
    }
    __syncthreads();                      // bar2

    // ---- B-frags for L3: read sH2 once into registers
    half8 bf3[4][4];
#pragma unroll
    for (int ks = 0; ks < 4; ++ks)
#pragma unroll
      for (int nt = 0; nt < 4; ++nt)
        bf3[ks][nt] = *(const half8*)&sH2[ks * 4 + q][nt * 16 + ml][0];

    // ---- L3: 4 slabs (mt = w*4+s); register-only epilogue (rm accumulate)
#pragma unroll
    for (int s = 0; s < 4; ++s) {
      float4 b3v = *(const float4*)&b3[(w * 4 + s) * 16 + q * 4];
      f32x4 acc3[4] = {};
#pragma unroll
      for (int ks = 0; ks < 4; ++ks)
#pragma unroll
        for (int nt = 0; nt < 4; ++nt)
          acc3[nt] = __builtin_amdgcn_mfma_f32_16x16x32_f16(
              a3c[ks], bf3[ks][nt], acc3[nt], 0, 0, 0);
      // refill a3c for slab (s+1)&3 right after last use
#pragma unroll
      for (int ks = 0; ks < 4; ++ks)
        a3c[ks] = W3F[((w * 4 + ((s + 1) & 3)) * 4 + ks) * 64 + l];
      // bias + validity, accumulate into rm (ReLU implicit: rm >= 0)
      float bb[4] = {b3v.x, b3v.y, b3v.z, b3v.w};
#pragma unroll
      for (int nt = 0; nt < 4; ++nt) {
        bool ok = (nt * 16 + ml) < v;
#pragma unroll
        for (int r = 0; r < 4; ++r) {
          float val = acc3[nt][r] + bb[r];
          if (ok) rm[s][r] = fmaxf(rm[s][r], val);
        }
      }
    }
  }

  // ---- once per block: reduce over the 16 points-in-group lanes + atomics
#pragma unroll
  for (int s = 0; s < 4; ++s)
#pragma unroll
    for (int r = 0; r < 4; ++r) {
      float m = rm[s][r];
      m = fmaxf(m, __shfl_xor(m, 1));
      m = fmaxf(m, __shfl_xor(m, 2));
      m = fmaxf(m, __shfl_xor(m, 4));
      m = fmaxf(m, __shfl_xor(m, 8));
      if (ml == 0)
        atomicMax(&aggU[(w * 4 + s) * 16 + q * 4 + r], __float_as_uint(m));
    }
}

// rho MLP, fp32, one block per batch row; 4-way split accumulators for ILP
__global__ void rho_kernel(const unsigned char* __restrict__ ws,
                           const float* __restrict__ r1w, const float* __restrict__ r1b,
                           const float* __restrict__ r2w, const float* __restrict__ r2b,
                           const float* __restrict__ r3w, const float* __restrict__ r3b,
                           float* __restrict__ out) {
  __shared__ float sa[R1], sz1[R1], sz2[R2];
  int b = blockIdx.x, t = threadIdx.x;
  const float* agg = (const float*)(ws + AGG_OFF) + b * P3;
  sa[t] = agg[t];
  __syncthreads();
  {
    float p0 = 0.f, p1 = 0.f, p2 = 0.f, p3 = 0.f;
#pragma unroll 8
    for (int k = 0; k < 64; ++k) {
      p0 = fmaf(sa[k],       r1w[k * R1 + t],         p0);
      p1 = fmaf(sa[k + 64],  r1w[(k + 64) * R1 + t],  p1);
      p2 = fmaf(sa[k + 128], r1w[(k + 128) * R1 + t], p2);
      p3 = fmaf(sa[k + 192], r1w[(k + 192) * R1 + t], p3);
    }
    sz1[t] = fmaxf(r1b[t] + ((p0 + p1) + (p2 + p3)), 0.f);
  }
  __syncthreads();
  if (t < R2) {
    float p0 = 0.f, p1 = 0.f, p2 = 0.f, p3 = 0.f;
#pragma unroll 8
    for (int k = 0; k < 64; ++k) {
      p0 = fmaf(sz1[k],       r2w[k * R2 + t],         p0);
      p1 = fmaf(sz1[k + 64],  r2w[(k + 64) * R2 + t],  p1);
      p2 = fmaf(sz1[k + 128], r2w[(k + 128) * R2 + t], p2);
      p3 = fmaf(sz1[k + 192], r2w[(k + 192) * R2 + t], p3);
    }
    sz2[t] = fmaxf(r2b[t] + ((p0 + p1) + (p2 + p3)), 0.f);
  }
  __syncthreads();
  if (t < OUTD) {
    float p0 = 0.f, p1 = 0.f;
#pragma unroll 8
    for (int k = 0; k < 64; ++k) {
      p0 = fmaf(sz2[k],      r3w[k * OUTD + t],        p0);
      p1 = fmaf(sz2[k + 64], r3w[(k + 64) * OUTD + t], p1);
    }
    out[b * OUTD + t] = r3b[t] + p0 + p1;
  }
}

extern "C" void kernel_launch(void* const* d_in, const int* in_sizes, int n_in,
                              void* d_out, int out_size, void* d_ws, size_t ws_size,
                              hipStream_t stream) {
  const float* pts     = (const float*)d_in[0];
  const int*   lengths = (const int*)d_in[1];
  const float* w1  = (const float*)d_in[2];
  const float* b1  = (const float*)d_in[3];
  const float* w2  = (const float*)d_in[4];
  const float* b2  = (const float*)d_in[5];
  const float* w3  = (const float*)d_in[6];
  const float* b3  = (const float*)d_in[7];
  const float* r1w = (const float*)d_in[8];
  const float* r1b = (const float*)d_in[9];
  const float* r2w = (const float*)d_in[10];
  const float* r2b = (const float*)d_in[11];
  const float* r3w = (const float*)d_in[12];
  const float* r3b = (const float*)d_in[13];
  unsigned char* ws = (unsigned char*)d_ws;

  prep_kernel<<<160, 256, 0, stream>>>(w2, w3, ws);
  phi_kernel<<<PGRID, 256, 0, stream>>>(pts, lengths, w1, b1, b2, b3, ws);
  rho_kernel<<<BB, 256, 0, stream>>>(ws, r1w, r1b, r2w, r2b, r3w, r3b, (float*)d_out);
}

// Round 7
// 194.798 us; speedup vs baseline: 1.2529x; 1.2529x over previous
//
#include <hip/hip_runtime.h>
#include <hip/hip_fp16.h>

#define BB   128
#define NN   4096
#define OUTD 64
#define P1   64
#define P2   128
#define P3   256
#define R1   256
#define R2   128
#define CHUNK 64
#define NCHK (NN / CHUNK)     // 64 chunk positions per batch
#define GPB  6                // blocks per batch
#define PGRID (BB * GPB)      // 768 = 3 blocks/CU resident at (256,3)

typedef _Float16 half8 __attribute__((ext_vector_type(8)));
typedef _Float16 half4 __attribute__((ext_vector_type(4)));
typedef float    f32x4 __attribute__((ext_vector_type(4)));

// workspace layout
#define AGG_OFF 0                        // 128*256 u32 (fp32 bits) = 131072 B
#define W2F_OFF (BB * P3 * 4)            // W2 A-frags fp16, 16 frags x 1KB = 16384 B
#define W3F_OFF (W2F_OFF + P2 * P1 * 2)  // W3 A-frags fp16, 64 frags x 1KB = 65536 B

// prep: zero agg + swizzle w2/w3 into MFMA A-fragment order.
// frag f element (l, j): W[ch = mt*16 + (l&15)][k = ks*32 + (l>>4)*8 + j]
__global__ void prep_kernel(const float* __restrict__ w2, const float* __restrict__ w3,
                            unsigned char* ws) {
  int idx = blockIdx.x * 256 + threadIdx.x;
  if (idx < BB * P3) ((unsigned*)(ws + AGG_OFF))[idx] = 0u;   // agg = +0.0f
  _Float16* W2F = (_Float16*)(ws + W2F_OFF);
  _Float16* W3F = (_Float16*)(ws + W3F_OFF);
  if (idx < P1 * P2) {                       // 16 frags (mt:8, ks:2)
    int f = idx >> 9, rem = idx & 511, l = rem >> 3, j = rem & 7;
    int mt = f >> 1, ks = f & 1;
    int ch = mt * 16 + (l & 15), k = ks * 32 + (l >> 4) * 8 + j;
    W2F[idx] = (_Float16)w2[k * P2 + ch];
  }
  int i2 = idx - P1 * P2;
  if (i2 >= 0 && i2 < P2 * P3) {             // 64 frags (mt:16, ks:4)
    int f = i2 >> 9, rem = i2 & 511, l = rem >> 3, j = rem & 7;
    int mt = f >> 2, ks = f & 3;
    int ch = mt * 16 + (l & 15), k = ks * 32 + (l >> 4) * 8 + j;
    W3F[i2] = (_Float16)w3[k * P3 + ch];
  }
}

// phi: persistent blocks, grid 768 (b = bid&127 fixed per block; chunks
// c = g, g+6, ... while c*64 < len).
//
// SPILL RULE (R4/R5/R6 post-mortems, 3 failures): any half8 fragment vector
// that is loop-carried across the barrier-containing item loop gets demoted
// to scratch by the compiler (FETCH/WRITE -> 60-130MB, 2-3x slower) even
// with nominal register headroom. Therefore:
//   * loop-carried state is ONLY rm[4][4] (16 floats, every index static)
//     + scalars. a2/a3c are loaded per item from L2 (cheap, hidden under
//     L1 as in R2) and DIE before the back edge.
//   * no bf3[4][4] caching (64-reg transient): L3 reads sH2 inline per
//     (ks,nt) -- R0-proven pattern, cost ~2us, removes the pressure spike.
// Persistence wins kept:
//   * per-item epilogue (64 shuffles + 16 atomics + vmcnt drain at next
//     barrier -- the largest per-item stall) becomes register fmax into rm;
//     ONE shuffle-reduce + atomicMax pass per block (atomics /21).
//   * 4096 empty-chunk dispatches gone; setup/dispatch churn gone.
// Barrier audit: no continue; trip count uniform (len, g block-uniform);
// return-guard before any barrier. Two barriers per item:
//   [L1 w:sH1] bar1 [L2 r:sH1 w:sH2] bar2 [L3 r:sH2 regs-only]
// Item k+1 writes sH1 only after bar2(k); writes sH2 only after bar1(k+1),
// by which point all waves finished their L3(k) sH2 reads. Safe.
__launch_bounds__(256, 3)
__global__ void phi_kernel(const float* __restrict__ pts, const int* __restrict__ lengths,
                           const float* __restrict__ w1, const float* __restrict__ b1,
                           const float* __restrict__ b2, const float* __restrict__ b3,
                           unsigned char* ws) {
  __shared__ __align__(16) _Float16 sH1[8][CHUNK][8];    //  8 KB
  __shared__ __align__(16) _Float16 sH2[16][CHUNK][8];   // 16 KB

  int bid = blockIdx.x;
  int b = bid & (BB - 1), g = bid >> 7;
  int len = lengths[b];
  if (g * CHUNK >= len) return;           // block-uniform, before any barrier

  int t = threadIdx.x;
  int w = t >> 6, l = t & 63;
  int ml = l & 15, q = l >> 4;

  const half8* W2F = (const half8*)(ws + W2F_OFF);  // 64 half8 per frag
  const half8* W3F = (const half8*)(ws + W3F_OFF);
  const float2* Pp = (const float2*)pts + (size_t)b * NN;

  // cross-item max accumulator: ONLY loop-carried vector state (static idx).
  // rm >= 0 always (ReLU) and agg init is +0.0f, so starting at 0 is exact.
  float rm[4][4] = {};

  for (int c = g; c * CHUNK < len; c += GPB) {
    int v = min(CHUNK, len - c * CHUNK);

    // per-item weight fragments (die before the back edge -- spill rule)
    half8 a2[2][2];
#pragma unroll
    for (int mt2 = 0; mt2 < 2; ++mt2)
#pragma unroll
      for (int ks = 0; ks < 2; ++ks)
        a2[mt2][ks] = W2F[((w * 2 + mt2) * 2 + ks) * 64 + l];
    half8 a3c[4];
#pragma unroll
    for (int ks = 0; ks < 4; ++ks)
      a3c[ks] = W3F[((w * 4 + 0) * 4 + ks) * 64 + l];

    // ---- L1 (K=2, VALU fp32): wave w computes ch [16w,16w+16) for 64 pts
    {
      float2 xy = Pp[c * CHUNK + l];
      half8 h8[2];
#pragma unroll
      for (int j = 0; j < 16; ++j) {
        int jj = w * 16 + j;                            // wave-uniform -> s_loads
        float h = fmaf(xy.y, w1[P1 + jj], fmaf(xy.x, w1[jj], b1[jj]));
        h8[j >> 3][j & 7] = (_Float16)fmaxf(h, 0.f);
      }
      *(half8*)&sH1[w * 2][l][0]     = h8[0];
      *(half8*)&sH1[w * 2 + 1][l][0] = h8[1];
    }
    __syncthreads();                      // bar1

    // ---- L2: h2^T[128][64] = W2^T x h1^T  (16 MFMAs/wave)
    {
      f32x4 acc2[2][4] = {};
#pragma unroll
      for (int ks = 0; ks < 2; ++ks) {
        half8 bf[4];
#pragma unroll
        for (int nt = 0; nt < 4; ++nt)
          bf[nt] = *(const half8*)&sH1[ks * 4 + q][nt * 16 + ml][0];
#pragma unroll
        for (int mt2 = 0; mt2 < 2; ++mt2)
#pragma unroll
          for (int nt = 0; nt < 4; ++nt)
            acc2[mt2][nt] = __builtin_amdgcn_mfma_f32_16x16x32_f16(
                a2[mt2][ks], bf[nt], acc2[mt2][nt], 0, 0, 0);
      }
      // epilogue: bias+ReLU; lane holds 4 consecutive ch -> packed 8B writes
#pragma unroll
      for (int mt2 = 0; mt2 < 2; ++mt2) {
        float4 b2v = *(const float4*)&b2[(w * 2 + mt2) * 16 + q * 4];
#pragma unroll
        for (int nt = 0; nt < 4; ++nt) {
          half4 hp;
          hp[0] = (_Float16)fmaxf(acc2[mt2][nt][0] + b2v.x, 0.f);
          hp[1] = (_Float16)fmaxf(acc2[mt2][nt][1] + b2v.y, 0.f);
          hp[2] = (_Float16)fmaxf(acc2[mt2][nt][2] + b2v.z, 0.f);
          hp[3] = (_Float16)fmaxf(acc2[mt2][nt][3] + b2v.w, 0.f);
          *(half4*)&sH2[(w * 2 + mt2) * 2 + (q >> 1)][nt * 16 + ml][(q & 1) * 4] = hp;
        }
      }
    }
    __syncthreads();                      // bar2

    // ---- L3: 4 slabs (mt = w*4+s); sH2 read inline (no bf3 cache);
    // register-only epilogue accumulating into rm.
#pragma unroll
    for (int s = 0; s < 4; ++s) {
      float4 b3v = *(const float4*)&b3[(w * 4 + s) * 16 + q * 4];
      f32x4 acc3[4] = {};
#pragma unroll
      for (int ks = 0; ks < 4; ++ks)
#pragma unroll
        for (int nt = 0; nt < 4; ++nt) {
          half8 bf = *(const half8*)&sH2[ks * 4 + q][nt * 16 + ml][0];
          acc3[nt] = __builtin_amdgcn_mfma_f32_16x16x32_f16(
              a3c[ks], bf, acc3[nt], 0, 0, 0);
        }
      // refill a3c for next slab after last use (s<3 only; a3c dies at s=3)
      if (s < 3) {
#pragma unroll
        for (int ks = 0; ks < 4; ++ks)
          a3c[ks] = W3F[((w * 4 + s + 1) * 4 + ks) * 64 + l];
      }
      float bb[4] = {b3v.x, b3v.y, b3v.z, b3v.w};
#pragma unroll
      for (int nt = 0; nt < 4; ++nt) {
        bool ok = (nt * 16 + ml) < v;
#pragma unroll
        for (int r = 0; r < 4; ++r) {
          float val = acc3[nt][r] + bb[r];
          if (ok) rm[s][r] = fmaxf(rm[s][r], val);
        }
      }
    }
  }

  // ---- once per block: reduce over the 16 ml lanes + atomics
  unsigned* aggU = (unsigned*)(ws + AGG_OFF) + b * P3;
#pragma unroll
  for (int s = 0; s < 4; ++s)
#pragma unroll
    for (int r = 0; r < 4; ++r) {
      float m = rm[s][r];
      m = fmaxf(m, __shfl_xor(m, 1));
      m = fmaxf(m, __shfl_xor(m, 2));
      m = fmaxf(m, __shfl_xor(m, 4));
      m = fmaxf(m, __shfl_xor(m, 8));
      if (ml == 0)
        atomicMax(&aggU[(w * 4 + s) * 16 + q * 4 + r], __float_as_uint(m));
    }
}

// rho MLP, fp32, one block per batch row; 4-way split accumulators for ILP
__global__ void rho_kernel(const unsigned char* __restrict__ ws,
                           const float* __restrict__ r1w, const float* __restrict__ r1b,
                           const float* __restrict__ r2w, const float* __restrict__ r2b,
                           const float* __restrict__ r3w, const float* __restrict__ r3b,
                           float* __restrict__ out) {
  __shared__ float sa[R1], sz1[R1], sz2[R2];
  int b = blockIdx.x, t = threadIdx.x;
  const float* agg = (const float*)(ws + AGG_OFF) + b * P3;
  sa[t] = agg[t];
  __syncthreads();
  {
    float p0 = 0.f, p1 = 0.f, p2 = 0.f, p3 = 0.f;
#pragma unroll 8
    for (int k = 0; k < 64; ++k) {
      p0 = fmaf(sa[k],       r1w[k * R1 + t],         p0);
      p1 = fmaf(sa[k + 64],  r1w[(k + 64) * R1 + t],  p1);
      p2 = fmaf(sa[k + 128], r1w[(k + 128) * R1 + t], p2);
      p3 = fmaf(sa[k + 192], r1w[(k + 192) * R1 + t], p3);
    }
    sz1[t] = fmaxf(r1b[t] + ((p0 + p1) + (p2 + p3)), 0.f);
  }
  __syncthreads();
  if (t < R2) {
    float p0 = 0.f, p1 = 0.f, p2 = 0.f, p3 = 0.f;
#pragma unroll 8
    for (int k = 0; k < 64; ++k) {
      p0 = fmaf(sz1[k],       r2w[k * R2 + t],         p0);
      p1 = fmaf(sz1[k + 64],  r2w[(k + 64) * R2 + t],  p1);
      p2 = fmaf(sz1[k + 128], r2w[(k + 128) * R2 + t], p2);
      p3 = fmaf(sz1[k + 192], r2w[(k + 192) * R2 + t], p3);
    }
    sz2[t] = fmaxf(r2b[t] + ((p0 + p1) + (p2 + p3)), 0.f);
  }
  __syncthreads();
  if (t < OUTD) {
    float p0 = 0.f, p1 = 0.f;
#pragma unroll 8
    for (int k = 0; k < 64; ++k) {
      p0 = fmaf(sz2[k],      r3w[k * OUTD + t],        p0);
      p1 = fmaf(sz2[k + 64], r3w[(k + 64) * OUTD + t], p1);
    }
    out[b * OUTD + t] = r3b[t] + p0 + p1;
  }
}

extern "C" void kernel_launch(void* const* d_in, const int* in_sizes, int n_in,
                              void* d_out, int out_size, void* d_ws, size_t ws_size,
                              hipStream_t stream) {
  const float* pts     = (const float*)d_in[0];
  const int*   lengths = (const int*)d_in[1];
  const float* w1  = (const float*)d_in[2];
  const float* b1  = (const float*)d_in[3];
  const float* w2  = (const float*)d_in[4];
  const float* b2  = (const float*)d_in[5];
  const float* w3  = (const float*)d_in[6];
  const float* b3  = (const float*)d_in[7];
  const float* r1w = (const float*)d_in[8];
  const float* r1b = (const float*)d_in[9];
  const float* r2w = (const float*)d_in[10];
  const float* r2b = (const float*)d_in[11];
  const float* r3w = (const float*)d_in[12];
  const float* r3b = (const float*)d_in[13];
  unsigned char* ws = (unsigned char*)d_ws;

  prep_kernel<<<160, 256, 0, stream>>>(w2, w3, ws);
  phi_kernel<<<PGRID, 256, 0, stream>>>(pts, lengths, w1, b1, b2, b3, ws);
  rho_kernel<<<BB, 256, 0, stream>>>(ws, r1w, r1b, r2w, r2b, r3w, r3b, (float*)d_out);
}

// Round 8
// 156.292 us; speedup vs baseline: 1.5616x; 1.2464x over previous
//
#include <hip/hip_runtime.h>
#include <hip/hip_fp16.h>

#define BB   128
#define NN   4096
#define OUTD 64
#define P1   64
#define P2   128
#define P3   256
#define R1   256
#define R2   128
#define CHUNK 64
#define NCHK (NN / CHUNK)     // 64 chunk positions per batch
#define GPB  6                // blocks per batch
#define PGRID (BB * GPB)      // 768 = 3 blocks/CU resident at (256,3)

typedef _Float16 half8 __attribute__((ext_vector_type(8)));
typedef _Float16 half4 __attribute__((ext_vector_type(4)));
typedef float    f32x4 __attribute__((ext_vector_type(4)));

// workspace layout
#define AGG_OFF 0                        // 128*256 u32 (fp32 bits) = 131072 B
#define W2F_OFF (BB * P3 * 4)            // W2 A-frags fp16, 16 frags x 1KB = 16384 B
#define W3F_OFF (W2F_OFF + P2 * P1 * 2)  // W3 A-frags fp16, 64 frags x 1KB = 65536 B

// prep: zero agg + swizzle w2/w3 into MFMA A-fragment order.
// frag f element (l, j): W[ch = mt*16 + (l&15)][k = ks*32 + (l>>4)*8 + j]
__global__ void prep_kernel(const float* __restrict__ w2, const float* __restrict__ w3,
                            unsigned char* ws) {
  int idx = blockIdx.x * 256 + threadIdx.x;
  if (idx < BB * P3) ((unsigned*)(ws + AGG_OFF))[idx] = 0u;   // agg = +0.0f
  _Float16* W2F = (_Float16*)(ws + W2F_OFF);
  _Float16* W3F = (_Float16*)(ws + W3F_OFF);
  if (idx < P1 * P2) {                       // 16 frags (mt:8, ks:2)
    int f = idx >> 9, rem = idx & 511, l = rem >> 3, j = rem & 7;
    int mt = f >> 1, ks = f & 1;
    int ch = mt * 16 + (l & 15), k = ks * 32 + (l >> 4) * 8 + j;
    W2F[idx] = (_Float16)w2[k * P2 + ch];
  }
  int i2 = idx - P1 * P2;
  if (i2 >= 0 && i2 < P2 * P3) {             // 64 frags (mt:16, ks:4)
    int f = i2 >> 9, rem = i2 & 511, l = rem >> 3, j = rem & 7;
    int mt = f >> 2, ks = f & 3;
    int ch = mt * 16 + (l & 15), k = ks * 32 + (l >> 4) * 8 + j;
    W3F[i2] = (_Float16)w3[k * P3 + ch];
  }
}

// phi: persistent blocks, grid 768 (b = bid&127 fixed per block; chunks
// c = g, g+6, ... while c*64 < len).
//
// SPILL SAGA (R4-R7): any weight-fragment value the compiler can keep live
// across the barrier-containing item loop WILL be kept live and then spilled
// (FETCH/WRITE tens of MB, 2-3x slower). R7 showed that writing the loads
// inside the loop is NOT enough: the addresses are loop-invariant and no
// in-loop store aliases ws, so redundant-load elimination re-hoists them
// (VGPR 84, 48MB FETCH). FIX: launder the weight/bias pointers through an
// empty asm volatile INSIDE the loop -- address becomes opaque per
// iteration, cross-iteration CSE is impossible, fragment values die each
// item. Reloads come from L2 (~350B/lane/item) hidden under L1/epilogue;
// R2's non-persistent kernel paid exactly this per chunk anyway.
//
// Loop-carried state: rm[4][4] (16 floats, all indices static) + scalars.
// Persistence wins: per-item epilogue (64 shuffles + 16 atomics + vmcnt
// drain) -> register fmax; ONE reduce+atomic pass per block (atomics /21);
// empty-chunk dispatches gone; setup amortized.
// Barrier audit: no continue; trip count uniform per block (len, g
// block-uniform); return-guard before any barrier. Two barriers per item:
//   [L1 w:sH1] bar1 [L2 r:sH1 w:sH2] bar2 [L3 r:sH2 regs-only]
// Item k+1 writes sH1 only after bar2(k); writes sH2 only after bar1(k+1),
// by which point all waves finished their L3(k) sH2 reads. Safe.
__launch_bounds__(256, 3)
__global__ void phi_kernel(const float* __restrict__ pts, const int* __restrict__ lengths,
                           const float* __restrict__ w1, const float* __restrict__ b1,
                           const float* __restrict__ b2, const float* __restrict__ b3,
                           unsigned char* ws) {
  __shared__ __align__(16) _Float16 sH1[8][CHUNK][8];    //  8 KB
  __shared__ __align__(16) _Float16 sH2[16][CHUNK][8];   // 16 KB

  int bid = blockIdx.x;
  int b = bid & (BB - 1), g = bid >> 7;
  int len = lengths[b];
  if (g * CHUNK >= len) return;           // block-uniform, before any barrier

  int t = threadIdx.x;
  int w = t >> 6, l = t & 63;
  int ml = l & 15, q = l >> 4;

  const float2* Pp = (const float2*)pts + (size_t)b * NN;

  // cross-item max accumulator: ONLY loop-carried vector state (static idx).
  // rm >= 0 always (ReLU) and agg init is +0.0f, so starting at 0 is exact.
  float rm[4][4] = {};

  for (int c = g; c * CHUNK < len; c += GPB) {
    int v = min(CHUNK, len - c * CHUNK);

    // ---- pointer laundering: opaque per iteration -> loads below cannot be
    // CSE'd/hoisted across the back edge (the R7 spill mechanism).
    const half8* W2F = (const half8*)(ws + W2F_OFF);
    const half8* W3F = (const half8*)(ws + W3F_OFF);
    const float* b2p = b2;
    const float* b3p = b3;
    asm volatile("" : "+s"(W2F), "+s"(W3F), "+s"(b2p), "+s"(b3p));

    // per-item weight fragments (die before the back edge)
    half8 a2[2][2];
#pragma unroll
    for (int mt2 = 0; mt2 < 2; ++mt2)
#pragma unroll
      for (int ks = 0; ks < 2; ++ks)
        a2[mt2][ks] = W2F[((w * 2 + mt2) * 2 + ks) * 64 + l];
    half8 a3c[4];
#pragma unroll
    for (int ks = 0; ks < 4; ++ks)
      a3c[ks] = W3F[((w * 4 + 0) * 4 + ks) * 64 + l];

    // ---- L1 (K=2, VALU fp32): wave w computes ch [16w,16w+16) for 64 pts
    {
      float2 xy = Pp[c * CHUNK + l];
      half8 h8[2];
#pragma unroll
      for (int j = 0; j < 16; ++j) {
        int jj = w * 16 + j;                            // wave-uniform -> s_loads
        float h = fmaf(xy.y, w1[P1 + jj], fmaf(xy.x, w1[jj], b1[jj]));
        h8[j >> 3][j & 7] = (_Float16)fmaxf(h, 0.f);
      }
      *(half8*)&sH1[w * 2][l][0]     = h8[0];
      *(half8*)&sH1[w * 2 + 1][l][0] = h8[1];
    }
    __syncthreads();                      // bar1

    // ---- L2: h2^T[128][64] = W2^T x h1^T  (16 MFMAs/wave)
    {
      f32x4 acc2[2][4] = {};
#pragma unroll
      for (int ks = 0; ks < 2; ++ks) {
        half8 bf[4];
#pragma unroll
        for (int nt = 0; nt < 4; ++nt)
          bf[nt] = *(const half8*)&sH1[ks * 4 + q][nt * 16 + ml][0];
#pragma unroll
        for (int mt2 = 0; mt2 < 2; ++mt2)
#pragma unroll
          for (int nt = 0; nt < 4; ++nt)
            acc2[mt2][nt] = __builtin_amdgcn_mfma_f32_16x16x32_f16(
                a2[mt2][ks], bf[nt], acc2[mt2][nt], 0, 0, 0);
      }
      // epilogue: bias+ReLU; lane holds 4 consecutive ch -> packed 8B writes
#pragma unroll
      for (int mt2 = 0; mt2 < 2; ++mt2) {
        float4 b2v = *(const float4*)&b2p[(w * 2 + mt2) * 16 + q * 4];
#pragma unroll
        for (int nt = 0; nt < 4; ++nt) {
          half4 hp;
          hp[0] = (_Float16)fmaxf(acc2[mt2][nt][0] + b2v.x, 0.f);
          hp[1] = (_Float16)fmaxf(acc2[mt2][nt][1] + b2v.y, 0.f);
          hp[2] = (_Float16)fmaxf(acc2[mt2][nt][2] + b2v.z, 0.f);
          hp[3] = (_Float16)fmaxf(acc2[mt2][nt][3] + b2v.w, 0.f);
          *(half4*)&sH2[(w * 2 + mt2) * 2 + (q >> 1)][nt * 16 + ml][(q & 1) * 4] = hp;
        }
      }
    }
    __syncthreads();                      // bar2

    // ---- L3: 4 slabs (mt = w*4+s); sH2 read inline (no bf3 cache);
    // register-only epilogue accumulating into rm.
#pragma unroll
    for (int s = 0; s < 4; ++s) {
      float4 b3v = *(const float4*)&b3p[(w * 4 + s) * 16 + q * 4];
      f32x4 acc3[4] = {};
#pragma unroll
      for (int ks = 0; ks < 4; ++ks)
#pragma unroll
        for (int nt = 0; nt < 4; ++nt) {
          half8 bf = *(const half8*)&sH2[ks * 4 + q][nt * 16 + ml][0];
          acc3[nt] = __builtin_amdgcn_mfma_f32_16x16x32_f16(
              a3c[ks], bf, acc3[nt], 0, 0, 0);
        }
      // refill a3c for next slab after last use (s<3 only; a3c dies at s=3)
      if (s < 3) {
#pragma unroll
        for (int ks = 0; ks < 4; ++ks)
          a3c[ks] = W3F[((w * 4 + s + 1) * 4 + ks) * 64 + l];
      }
      float bb[4] = {b3v.x, b3v.y, b3v.z, b3v.w};
#pragma unroll
      for (int nt = 0; nt < 4; ++nt) {
        bool ok = (nt * 16 + ml) < v;
#pragma unroll
        for (int r = 0; r < 4; ++r) {
          float val = acc3[nt][r] + bb[r];
          if (ok) rm[s][r] = fmaxf(rm[s][r], val);
        }
      }
    }
  }

  // ---- once per block: reduce over the 16 ml lanes + atomics
  unsigned* aggU = (unsigned*)(ws + AGG_OFF) + b * P3;
#pragma unroll
  for (int s = 0; s < 4; ++s)
#pragma unroll
    for (int r = 0; r < 4; ++r) {
      float m = rm[s][r];
      m = fmaxf(m, __shfl_xor(m, 1));
      m = fmaxf(m, __shfl_xor(m, 2));
      m = fmaxf(m, __shfl_xor(m, 4));
      m = fmaxf(m, __shfl_xor(m, 8));
      if (ml == 0)
        atomicMax(&aggU[(w * 4 + s) * 16 + q * 4 + r], __float_as_uint(m));
    }
}

// rho MLP, fp32, one block per batch row; 4-way split accumulators for ILP
__global__ void rho_kernel(const unsigned char* __restrict__ ws,
                           const float* __restrict__ r1w, const float* __restrict__ r1b,
                           const float* __restrict__ r2w, const float* __restrict__ r2b,
                           const float* __restrict__ r3w, const float* __restrict__ r3b,
                           float* __restrict__ out) {
  __shared__ float sa[R1], sz1[R1], sz2[R2];
  int b = blockIdx.x, t = threadIdx.x;
  const float* agg = (const float*)(ws + AGG_OFF) + b * P3;
  sa[t] = agg[t];
  __syncthreads();
  {
    float p0 = 0.f, p1 = 0.f, p2 = 0.f, p3 = 0.f;
#pragma unroll 8
    for (int k = 0; k < 64; ++k) {
      p0 = fmaf(sa[k],       r1w[k * R1 + t],         p0);
      p1 = fmaf(sa[k + 64],  r1w[(k + 64) * R1 + t],  p1);
      p2 = fmaf(sa[k + 128], r1w[(k + 128) * R1 + t], p2);
      p3 = fmaf(sa[k + 192], r1w[(k + 192) * R1 + t], p3);
    }
    sz1[t] = fmaxf(r1b[t] + ((p0 + p1) + (p2 + p3)), 0.f);
  }
  __syncthreads();
  if (t < R2) {
    float p0 = 0.f, p1 = 0.f, p2 = 0.f, p3 = 0.f;
#pragma unroll 8
    for (int k = 0; k < 64; ++k) {
      p0 = fmaf(sz1[k],       r2w[k * R2 + t],         p0);
      p1 = fmaf(sz1[k + 64],  r2w[(k + 64) * R2 + t],  p1);
      p2 = fmaf(sz1[k + 128], r2w[(k + 128) * R2 + t], p2);
      p3 = fmaf(sz1[k + 192], r2w[(k + 192) * R2 + t], p3);
    }
    sz2[t] = fmaxf(r2b[t] + ((p0 + p1) + (p2 + p3)), 0.f);
  }
  __syncthreads();
  if (t < OUTD) {
    float p0 = 0.f, p1 = 0.f;
#pragma unroll 8
    for (int k = 0; k < 64; ++k) {
      p0 = fmaf(sz2[k],      r3w[k * OUTD + t],        p0);
      p1 = fmaf(sz2[k + 64], r3w[(k + 64) * OUTD + t], p1);
    }
    out[b * OUTD + t] = r3b[t] + p0 + p1;
  }
}

extern "C" void kernel_launch(void* const* d_in, const int* in_sizes, int n_in,
                              void* d_out, int out_size, void* d_ws, size_t ws_size,
                              hipStream_t stream) {
  const float* pts     = (const float*)d_in[0];
  const int*   lengths = (const int*)d_in[1];
  const float* w1  = (const float*)d_in[2];
  const float* b1  = (const float*)d_in[3];
  const float* w2  = (const float*)d_in[4];
  const float* b2  = (const float*)d_in[5];
  const float* w3  = (const float*)d_in[6];
  const float* b3  = (const float*)d_in[7];
  const float* r1w = (const float*)d_in[8];
  const float* r1b = (const float*)d_in[9];
  const float* r2w = (const float*)d_in[10];
  const float* r2b = (const float*)d_in[11];
  const float* r3w = (const float*)d_in[12];
  const float* r3b = (const float*)d_in[13];
  unsigned char* ws = (unsigned char*)d_ws;

  prep_kernel<<<160, 256, 0, stream>>>(w2, w3, ws);
  phi_kernel<<<PGRID, 256, 0, stream>>>(pts, lengths, w1, b1, b2, b3, ws);
  rho_kernel<<<BB, 256, 0, stream>>>(ws, r1w, r1b, r2w, r2b, r3w, r3b, (float*)d_out);
}

// Round 9
// 154.236 us; speedup vs baseline: 1.5824x; 1.0133x over previous
//
#include <hip/hip_runtime.h>
#include <hip/hip_fp16.h>

#define BB   128
#define NN   4096
#define OUTD 64
#define P1   64
#define P2   128
#define P3   256
#define R1   256
#define R2   128
#define CHUNK 64
#define NCHK (NN / CHUNK)     // 64 chunk positions per batch
#define GPB  16               // blocks per batch (R8 post-mortem: 6 -> 16)
#define PGRID (BB * GPB)      // 2048 blocks; 768 resident, rest queued

typedef _Float16 half8 __attribute__((ext_vector_type(8)));
typedef _Float16 half4 __attribute__((ext_vector_type(4)));
typedef float    f32x4 __attribute__((ext_vector_type(4)));

// workspace layout
#define AGG_OFF 0                        // 128*256 u32 (fp32 bits) = 131072 B
#define W2F_OFF (BB * P3 * 4)            // W2 A-frags fp16, 16 frags x 1KB = 16384 B
#define W3F_OFF (W2F_OFF + P2 * P1 * 2)  // W3 A-frags fp16, 64 frags x 1KB = 65536 B

// prep: zero agg + swizzle w2/w3 into MFMA A-fragment order.
// frag f element (l, j): W[ch = mt*16 + (l&15)][k = ks*32 + (l>>4)*8 + j]
__global__ void prep_kernel(const float* __restrict__ w2, const float* __restrict__ w3,
                            unsigned char* ws) {
  int idx = blockIdx.x * 256 + threadIdx.x;
  if (idx < BB * P3) ((unsigned*)(ws + AGG_OFF))[idx] = 0u;   // agg = +0.0f
  _Float16* W2F = (_Float16*)(ws + W2F_OFF);
  _Float16* W3F = (_Float16*)(ws + W3F_OFF);
  if (idx < P1 * P2) {                       // 16 frags (mt:8, ks:2)
    int f = idx >> 9, rem = idx & 511, l = rem >> 3, j = rem & 7;
    int mt = f >> 1, ks = f & 1;
    int ch = mt * 16 + (l & 15), k = ks * 32 + (l >> 4) * 8 + j;
    W2F[idx] = (_Float16)w2[k * P2 + ch];
  }
  int i2 = idx - P1 * P2;
  if (i2 >= 0 && i2 < P2 * P3) {             // 64 frags (mt:16, ks:4)
    int f = i2 >> 9, rem = i2 & 511, l = rem >> 3, j = rem & 7;
    int mt = f >> 2, ks = f & 3;
    int ch = mt * 16 + (l & 15), k = ks * 32 + (l >> 4) * 8 + j;
    W3F[i2] = (_Float16)w3[k * P3 + ch];
  }
}

// phi: persistent-ish blocks, grid 2048 (b = bid&127; g = bid>>7 in [0,16);
// chunks c = g, g+16, ... while c*64 < len -> max 4 items/block).
//
// R8 post-mortem: GPB=6 (grid 768, fully resident) was spill-free but SLOWER
// than the 4096-block R2 launch: occupancy 15% -- items within a block
// serialize on the ~6.3us per-item latency chain with no other blocks left
// to overlap, and makespan is set by max-len batches (11 serial items).
// Atomic-traffic reduction (WRITE 15->2.8MB) did NOT help => the lever is
// parallel slack, not epilogue traffic. GPB=16 restores overlap: critical
// path 4 items (~27us), 2048 blocks keep CUs backfilled as short/empty
// blocks retire, while persistence still amortizes setup and keeps ONE
// reduce+atomic pass per block.
//
// SPILL SAGA (R4-R7): any weight-fragment value the compiler can keep live
// across the barrier-containing item loop WILL be kept live and spilled
// (FETCH/WRITE tens of MB). Loads written inside the loop are NOT enough:
// loop-invariant addresses get re-hoisted by redundant-load elimination
// (R7: VGPR 84, 48MB FETCH). FIX (validated R8: FETCH 1.3MB): launder the
// weight/bias pointers through an empty asm volatile INSIDE the loop --
// address opaque per iteration, cross-iteration CSE impossible, fragment
// values die each item. Reloads are L2-resident, hidden under L1/epilogue.
//
// Loop-carried state: rm[4][4] (16 floats, all indices static) + scalars.
// Barrier audit: no continue; trip count uniform per block (len, g
// block-uniform); return-guard before any barrier. Two barriers per item:
//   [L1 w:sH1] bar1 [L2 r:sH1 w:sH2] bar2 [L3 r:sH2 regs-only]
// Item k+1 writes sH1 only after bar2(k); writes sH2 only after bar1(k+1),
// by which point all waves finished their L3(k) sH2 reads. Safe.
__launch_bounds__(256, 3)
__global__ void phi_kernel(const float* __restrict__ pts, const int* __restrict__ lengths,
                           const float* __restrict__ w1, const float* __restrict__ b1,
                           const float* __restrict__ b2, const float* __restrict__ b3,
                           unsigned char* ws) {
  __shared__ __align__(16) _Float16 sH1[8][CHUNK][8];    //  8 KB
  __shared__ __align__(16) _Float16 sH2[16][CHUNK][8];   // 16 KB

  int bid = blockIdx.x;
  int b = bid & (BB - 1), g = bid >> 7;
  int len = lengths[b];
  if (g * CHUNK >= len) return;           // block-uniform, before any barrier

  int t = threadIdx.x;
  int w = t >> 6, l = t & 63;
  int ml = l & 15, q = l >> 4;

  const float2* Pp = (const float2*)pts + (size_t)b * NN;

  // cross-item max accumulator: ONLY loop-carried vector state (static idx).
  // rm >= 0 always (ReLU) and agg init is +0.0f, so starting at 0 is exact.
  float rm[4][4] = {};

  for (int c = g; c * CHUNK < len; c += GPB) {
    int v = min(CHUNK, len - c * CHUNK);

    // ---- pointer laundering: opaque per iteration -> loads below cannot be
    // CSE'd/hoisted across the back edge (the R7 spill mechanism).
    const half8* W2F = (const half8*)(ws + W2F_OFF);
    const half8* W3F = (const half8*)(ws + W3F_OFF);
    const float* b2p = b2;
    const float* b3p = b3;
    asm volatile("" : "+s"(W2F), "+s"(W3F), "+s"(b2p), "+s"(b3p));

    // per-item weight fragments (die before the back edge)
    half8 a2[2][2];
#pragma unroll
    for (int mt2 = 0; mt2 < 2; ++mt2)
#pragma unroll
      for (int ks = 0; ks < 2; ++ks)
        a2[mt2][ks] = W2F[((w * 2 + mt2) * 2 + ks) * 64 + l];
    half8 a3c[4];
#pragma unroll
    for (int ks = 0; ks < 4; ++ks)
      a3c[ks] = W3F[((w * 4 + 0) * 4 + ks) * 64 + l];

    // ---- L1 (K=2, VALU fp32): wave w computes ch [16w,16w+16) for 64 pts
    {
      float2 xy = Pp[c * CHUNK + l];
      half8 h8[2];
#pragma unroll
      for (int j = 0; j < 16; ++j) {
        int jj = w * 16 + j;                            // wave-uniform -> s_loads
        float h = fmaf(xy.y, w1[P1 + jj], fmaf(xy.x, w1[jj], b1[jj]));
        h8[j >> 3][j & 7] = (_Float16)fmaxf(h, 0.f);
      }
      *(half8*)&sH1[w * 2][l][0]     = h8[0];
      *(half8*)&sH1[w * 2 + 1][l][0] = h8[1];
    }
    __syncthreads();                      // bar1

    // ---- L2: h2^T[128][64] = W2^T x h1^T  (16 MFMAs/wave)
    {
      f32x4 acc2[2][4] = {};
#pragma unroll
      for (int ks = 0; ks < 2; ++ks) {
        half8 bf[4];
#pragma unroll
        for (int nt = 0; nt < 4; ++nt)
          bf[nt] = *(const half8*)&sH1[ks * 4 + q][nt * 16 + ml][0];
#pragma unroll
        for (int mt2 = 0; mt2 < 2; ++mt2)
#pragma unroll
          for (int nt = 0; nt < 4; ++nt)
            acc2[mt2][nt] = __builtin_amdgcn_mfma_f32_16x16x32_f16(
                a2[mt2][ks], bf[nt], acc2[mt2][nt], 0, 0, 0);
      }
      // epilogue: bias+ReLU; lane holds 4 consecutive ch -> packed 8B writes
#pragma unroll
      for (int mt2 = 0; mt2 < 2; ++mt2) {
        float4 b2v = *(const float4*)&b2p[(w * 2 + mt2) * 16 + q * 4];
#pragma unroll
        for (int nt = 0; nt < 4; ++nt) {
          half4 hp;
          hp[0] = (_Float16)fmaxf(acc2[mt2][nt][0] + b2v.x, 0.f);
          hp[1] = (_Float16)fmaxf(acc2[mt2][nt][1] + b2v.y, 0.f);
          hp[2] = (_Float16)fmaxf(acc2[mt2][nt][2] + b2v.z, 0.f);
          hp[3] = (_Float16)fmaxf(acc2[mt2][nt][3] + b2v.w, 0.f);
          *(half4*)&sH2[(w * 2 + mt2) * 2 + (q >> 1)][nt * 16 + ml][(q & 1) * 4] = hp;
        }
      }
    }
    __syncthreads();                      // bar2

    // ---- L3: 4 slabs (mt = w*4+s); sH2 read inline (no bf3 cache);
    // register-only epilogue accumulating into rm.
#pragma unroll
    for (int s = 0; s < 4; ++s) {
      float4 b3v = *(const float4*)&b3p[(w * 4 + s) * 16 + q * 4];
      f32x4 acc3[4] = {};
#pragma unroll
      for (int ks = 0; ks < 4; ++ks)
#pragma unroll
        for (int nt = 0; nt < 4; ++nt) {
          half8 bf = *(const half8*)&sH2[ks * 4 + q][nt * 16 + ml][0];
          acc3[nt] = __builtin_amdgcn_mfma_f32_16x16x32_f16(
              a3c[ks], bf, acc3[nt], 0, 0, 0);
        }
      // refill a3c for next slab after last use (s<3 only; a3c dies at s=3)
      if (s < 3) {
#pragma unroll
        for (int ks = 0; ks < 4; ++ks)
          a3c[ks] = W3F[((w * 4 + s + 1) * 4 + ks) * 64 + l];
      }
      float bb[4] = {b3v.x, b3v.y, b3v.z, b3v.w};
#pragma unroll
      for (int nt = 0; nt < 4; ++nt) {
        bool ok = (nt * 16 + ml) < v;
#pragma unroll
        for (int r = 0; r < 4; ++r) {
          float val = acc3[nt][r] + bb[r];
          if (ok) rm[s][r] = fmaxf(rm[s][r], val);
        }
      }
    }
  }

  // ---- once per block: reduce over the 16 ml lanes + atomics
  unsigned* aggU = (unsigned*)(ws + AGG_OFF) + b * P3;
#pragma unroll
  for (int s = 0; s < 4; ++s)
#pragma unroll
    for (int r = 0; r < 4; ++r) {
      float m = rm[s][r];
      m = fmaxf(m, __shfl_xor(m, 1));
      m = fmaxf(m, __shfl_xor(m, 2));
      m = fmaxf(m, __shfl_xor(m, 4));
      m = fmaxf(m, __shfl_xor(m, 8));
      if (ml == 0)
        atomicMax(&aggU[(w * 4 + s) * 16 + q * 4 + r], __float_as_uint(m));
    }
}

// rho MLP, fp32, one block per batch row; 4-way split accumulators for ILP
__global__ void rho_kernel(const unsigned char* __restrict__ ws,
                           const float* __restrict__ r1w, const float* __restrict__ r1b,
                           const float* __restrict__ r2w, const float* __restrict__ r2b,
                           const float* __restrict__ r3w, const float* __restrict__ r3b,
                           float* __restrict__ out) {
  __shared__ float sa[R1], sz1[R1], sz2[R2];
  int b = blockIdx.x, t = threadIdx.x;
  const float* agg = (const float*)(ws + AGG_OFF) + b * P3;
  sa[t] = agg[t];
  __syncthreads();
  {
    float p0 = 0.f, p1 = 0.f, p2 = 0.f, p3 = 0.f;
#pragma unroll 8
    for (int k = 0; k < 64; ++k) {
      p0 = fmaf(sa[k],       r1w[k * R1 + t],         p0);
      p1 = fmaf(sa[k + 64],  r1w[(k + 64) * R1 + t],  p1);
      p2 = fmaf(sa[k + 128], r1w[(k + 128) * R1 + t], p2);
      p3 = fmaf(sa[k + 192], r1w[(k + 192) * R1 + t], p3);
    }
    sz1[t] = fmaxf(r1b[t] + ((p0 + p1) + (p2 + p3)), 0.f);
  }
  __syncthreads();
  if (t < R2) {
    float p0 = 0.f, p1 = 0.f, p2 = 0.f, p3 = 0.f;
#pragma unroll 8
    for (int k = 0; k < 64; ++k) {
      p0 = fmaf(sz1[k],       r2w[k * R2 + t],         p0);
      p1 = fmaf(sz1[k + 64],  r2w[(k + 64) * R2 + t],  p1);
      p2 = fmaf(sz1[k + 128], r2w[(k + 128) * R2 + t], p2);
      p3 = fmaf(sz1[k + 192], r2w[(k + 192) * R2 + t], p3);
    }
    sz2[t] = fmaxf(r2b[t] + ((p0 + p1) + (p2 + p3)), 0.f);
  }
  __syncthreads();
  if (t < OUTD) {
    float p0 = 0.f, p1 = 0.f;
#pragma unroll 8
    for (int k = 0; k < 64; ++k) {
      p0 = fmaf(sz2[k],      r3w[k * OUTD + t],        p0);
      p1 = fmaf(sz2[k + 64], r3w[(k + 64) * OUTD + t], p1);
    }
    out[b * OUTD + t] = r3b[t] + p0 + p1;
  }
}

extern "C" void kernel_launch(void* const* d_in, const int* in_sizes, int n_in,
                              void* d_out, int out_size, void* d_ws, size_t ws_size,
                              hipStream_t stream) {
  const float* pts     = (const float*)d_in[0];
  const int*   lengths = (const int*)d_in[1];
  const float* w1  = (const float*)d_in[2];
  const float* b1  = (const float*)d_in[3];
  const float* w2  = (const float*)d_in[4];
  const float* b2  = (const float*)d_in[5];
  const float* w3  = (const float*)d_in[6];
  const float* b3  = (const float*)d_in[7];
  const float* r1w = (const float*)d_in[8];
  const float* r1b = (const float*)d_in[9];
  const float* r2w = (const float*)d_in[10];
  const float* r2b = (const float*)d_in[11];
  const float* r3w = (const float*)d_in[12];
  const float* r3b = (const float*)d_in[13];
  unsigned char* ws = (unsigned char*)d_ws;

  prep_kernel<<<160, 256, 0, stream>>>(w2, w3, ws);
  phi_kernel<<<PGRID, 256, 0, stream>>>(pts, lengths, w1, b1, b2, b3, ws);
  rho_kernel<<<BB, 256, 0, stream>>>(ws, r1w, r1b, r2w, r2b, r3w, r3b, (float*)d_out);
}